// Round 10
// baseline (178.541 us; speedup 1.0000x reference)
//
#include <hip/hip_runtime.h>

#define BB 32
#define CC 128
#define HH 128
#define WW 128
#define HWSZ (HH * WW)          // 16384
#define CHW (CC * HWSZ)         // 2097152
#define S4 (HWSZ / 4)           // 4096
#define RPB 16                  // output rows per block
#define HALO 22                 // RPB + 6
#define NBAND (HH / RPB)        // 8

typedef float vfloat4 __attribute__((ext_vector_type(4)));

__device__ __forceinline__ vfloat4 fmax4(vfloat4 a, vfloat4 b) {
    vfloat4 r;
    r.x = fmaxf(a.x, b.x);
    r.y = fmaxf(a.y, b.y);
    r.z = fmaxf(a.z, b.z);
    r.w = fmaxf(a.w, b.w);
    return r;
}

// One block = (batch b, 16-row band). 256 blocks x 512 threads.
__global__ __launch_bounds__(512, 4) void sa_onepass(
    const float* __restrict__ x, const float* __restrict__ cw,
    float* __restrict__ out) {
    __shared__ float m_lds[2][HALO][WW];   // 22.0 KiB
    __shared__ float sig_lds[RPB][WW];     // 8 KiB
    __shared__ float wsh[2 * 49];

    const int tid = threadIdx.x;
    // XCD swizzle: same XCD gets 4 batches x all 8 bands -> halo neighbors co-XCD.
    const int wg  = blockIdx.x;            // 0..255
    const int xcd = wg & 7;
    const int lin = wg >> 3;               // 0..31
    const int b   = xcd * 4 + (lin >> 3);  // 0..31
    const int hb  = lin & 7;               // 0..7
    const int h0  = hb * RPB;

    if (tid < 98) wsh[tid] = cw[tid];

    const int r0 = tid >> 5;               // 0..15
    const int w4 = tid & 31;               // float4 column 0..31
    const float* xb = x + (size_t)b * CHW;

    // ---------- Phase 1: channel reduce halo rows h0-3 .. h0+18 ----------
    // A-position: halo row r0 (all threads). B-position: halo row r0+16
    // (r0 < 6 -> waves 0-2 only, wave-uniform).
    const bool actB = (r0 < HALO - RPB);   // r0 < 6
    const int gh_a = h0 - 3 + r0;
    const int gh_b = h0 - 3 + r0 + RPB;    // h0+13 .. h0+18
    const bool okA = (gh_a >= 0) && (gh_a < HH);
    const bool okB = actB && (gh_b < HH);
    const int cha = gh_a < 0 ? 0 : (gh_a > HH - 1 ? HH - 1 : gh_a);
    const int chb = gh_b > HH - 1 ? HH - 1 : gh_b;

    const vfloat4* pA = (const vfloat4*)(xb + cha * WW) + w4;
    const vfloat4* pB = (const vfloat4*)(xb + chb * WW) + w4;

    vfloat4 sumA, mxA;
    {
        vfloat4 v = pA[0];
        sumA = v; mxA = v;
    }
    #pragma unroll 8
    for (int c = 1; c < CC; ++c) {
        vfloat4 v = pA[(size_t)c * S4];
        sumA += v;
        mxA = fmax4(mxA, v);
    }
    vfloat4 sumB = {0.f, 0.f, 0.f, 0.f}, mxB = sumB;
    if (actB) {                             // waves 3-7 skip entirely
        vfloat4 v = pB[0];
        sumB = v; mxB = v;
        #pragma unroll 8
        for (int c = 1; c < CC; ++c) {
            vfloat4 t = pB[(size_t)c * S4];
            sumB += t;
            mxB = fmax4(mxB, t);
        }
    }

    const float invC = 1.0f / (float)CC;
    {
        vfloat4 avgA = sumA * invC;
        if (!okA) { avgA = (vfloat4){0,0,0,0}; mxA = (vfloat4){0,0,0,0}; }
        *(vfloat4*)&m_lds[0][r0][w4 * 4] = avgA;
        *(vfloat4*)&m_lds[1][r0][w4 * 4] = mxA;
        if (actB) {
            vfloat4 avgB = sumB * invC;
            if (!okB) { avgB = (vfloat4){0,0,0,0}; mxB = (vfloat4){0,0,0,0}; }
            *(vfloat4*)&m_lds[0][r0 + RPB][w4 * 4] = avgB;
            *(vfloat4*)&m_lds[1][r0 + RPB][w4 * 4] = mxB;
        }
    }
    __syncthreads();

    // ---------- Phase 2: conv 7x7 + sigmoid, conflict-free (R8 layout) ----
    // thread -> (q = tid>>7 in 0..3: row group of 4, w = tid&127: one column).
    {
        const int q = tid >> 7;            // 0..3 -> rows q*4 .. q*4+3
        const int w = tid & 127;
        float attn[4] = {0.f, 0.f, 0.f, 0.f};
        #pragma unroll
        for (int ic = 0; ic < 2; ++ic) {
            #pragma unroll
            for (int L = 0; L < 10; ++L) { // LDS row = q*4 + L (max 21)
                const float* row = &m_lds[ic][q * 4 + L][0];
                #pragma unroll
                for (int kw = 0; kw < 7; ++kw) {
                    int wi = w - 3 + kw;
                    float v = (wi >= 0 && wi < WW) ? row[wi] : 0.0f;
                    #pragma unroll
                    for (int j = 0; j < 4; ++j) {
                        const int kh = L - j;          // compile-time after unroll
                        if (kh >= 0 && kh <= 6)
                            attn[j] = fmaf(v, wsh[ic * 49 + kh * 7 + kw], attn[j]);
                    }
                }
            }
        }
        #pragma unroll
        for (int j = 0; j < 4; ++j)
            sig_lds[q * 4 + j][w] = 1.0f / (1.0f + __expf(-attn[j]));
    }
    __syncthreads();

    // ---------- Phase 3: out = x * sig; nt loads (single-use) + nt stores ----
    {
        vfloat4 sig = *(const vfloat4*)&sig_lds[r0][w4 * 4];
        const int s = (h0 + r0) * WW + w4 * 4;
        const vfloat4* px = (const vfloat4*)xb + (s >> 2);
        vfloat4* po = (vfloat4*)(out + (size_t)b * CHW) + (s >> 2);
        #pragma unroll 1
        for (int c0 = CC - 8; c0 >= 0; c0 -= 8) {
            vfloat4 v[8];
            #pragma unroll
            for (int j = 0; j < 8; ++j)
                v[j] = __builtin_nontemporal_load(px + (size_t)(c0 + 7 - j) * S4);
            #pragma unroll
            for (int j = 0; j < 8; ++j) {
                vfloat4 o = v[j] * sig;
                __builtin_nontemporal_store(o, po + (size_t)(c0 + 7 - j) * S4);
            }
        }
    }
}

extern "C" void kernel_launch(void* const* d_in, const int* in_sizes, int n_in,
                              void* d_out, int out_size, void* d_ws, size_t ws_size,
                              hipStream_t stream) {
    const float* x  = (const float*)d_in[0];
    const float* cw = (const float*)d_in[1];
    float* out = (float*)d_out;

    sa_onepass<<<BB * NBAND, 512, 0, stream>>>(x, cw, out);  // 256 blocks
}

// Round 11
// 140.860 us; speedup vs baseline: 1.2675x; 1.2675x over previous
//
#include <hip/hip_runtime.h>

#define BB 32
#define CC 128
#define HH 128
#define WW 128
#define HWSZ (HH * WW)          // 16384
#define CHW (CC * HWSZ)         // 2097152
#define S4 (HWSZ / 4)           // 4096
#define RPB 8                   // output rows per block
#define HALO 14                 // RPB + 6 (conv radius 3 each side)

typedef float vfloat4 __attribute__((ext_vector_type(4)));

__device__ __forceinline__ vfloat4 fmax4(vfloat4 a, vfloat4 b) {
    vfloat4 r;
    r.x = fmaxf(a.x, b.x);
    r.y = fmaxf(a.y, b.y);
    r.z = fmaxf(a.z, b.z);
    r.w = fmaxf(a.w, b.w);
    return r;
}

// One block = (batch b, 8-row band). Three phases, no global intermediates.
__global__ __launch_bounds__(256, 2) void sa_onepass(
    const float* __restrict__ x, const float* __restrict__ cw,
    float* __restrict__ out) {
    __shared__ float m_lds[2][HALO][WW];   // 14 KiB
    __shared__ float sig_lds[RPB][WW];     // 4 KiB
    __shared__ float wsh[2 * 49];

    const int tid = threadIdx.x;
    // XCD swizzle: adjacent h-bands of the same batch land on the same XCD.
    const int wg  = blockIdx.x;            // 0..511
    const int xcd = wg & 7;
    const int lin = wg >> 3;               // 0..63
    const int b   = xcd * 4 + (lin >> 4);  // 0..31
    const int hb  = lin & 15;              // 0..15
    const int h0  = hb * RPB;

    if (tid < 98) wsh[tid] = cw[tid];

    const int r0 = tid >> 5;               // 0..7
    const int w4 = tid & 31;               // float4 column 0..31
    const float* xb = x + (size_t)b * CHW;

    // ---------- Phase 1: channel reduce rows h0-3 .. h0+10 ----------
    const bool actB = (r0 < HALO - 8);     // r0 < 6 -> wave-uniform
    const int gh_a = h0 - 3 + r0;
    const int gh_b = h0 - 3 + r0 + 8;
    const bool okA = (gh_a >= 0) && (gh_a < HH);
    const bool okB = actB && (gh_b < HH);
    const int cha = gh_a < 0 ? 0 : (gh_a > HH - 1 ? HH - 1 : gh_a);
    const int chb = gh_b > HH - 1 ? HH - 1 : gh_b;

    const vfloat4* pA = (const vfloat4*)(xb + cha * WW) + w4;
    const vfloat4* pB = (const vfloat4*)(xb + chb * WW) + w4;

    vfloat4 sumA, mxA;
    {
        vfloat4 v = pA[0];
        sumA = v; mxA = v;
    }
    #pragma unroll 8
    for (int c = 1; c < CC; ++c) {
        vfloat4 v = pA[(size_t)c * S4];
        sumA += v;
        mxA = fmax4(mxA, v);
    }
    vfloat4 sumB = {0.f, 0.f, 0.f, 0.f}, mxB = sumB;
    if (actB) {                             // whole wave 3 skips
        vfloat4 v = pB[0];
        sumB = v; mxB = v;
        #pragma unroll 8
        for (int c = 1; c < CC; ++c) {
            vfloat4 t = pB[(size_t)c * S4];
            sumB += t;
            mxB = fmax4(mxB, t);
        }
    }

    const float invC = 1.0f / (float)CC;
    {
        vfloat4 avgA = sumA * invC;
        if (!okA) { avgA = (vfloat4){0,0,0,0}; mxA = (vfloat4){0,0,0,0}; }
        *(vfloat4*)&m_lds[0][r0][w4 * 4] = avgA;
        *(vfloat4*)&m_lds[1][r0][w4 * 4] = mxA;
        if (actB) {
            vfloat4 avgB = sumB * invC;
            if (!okB) { avgB = (vfloat4){0,0,0,0}; mxB = (vfloat4){0,0,0,0}; }
            *(vfloat4*)&m_lds[0][r0 + 8][w4 * 4] = avgB;
            *(vfloat4*)&m_lds[1][r0 + 8][w4 * 4] = mxB;
        }
    }
    __syncthreads();

    // ---------- Phase 2: conv 7x7 + sigmoid, conflict-free (R8 layout) ----
    {
        const int q = tid >> 7;            // 0..1 -> rows q*4 .. q*4+3
        const int w = tid & 127;
        float attn[4] = {0.f, 0.f, 0.f, 0.f};
        #pragma unroll
        for (int ic = 0; ic < 2; ++ic) {
            #pragma unroll
            for (int L = 0; L < 10; ++L) { // LDS row = q*4 + L
                const float* row = &m_lds[ic][q * 4 + L][0];
                #pragma unroll
                for (int kw = 0; kw < 7; ++kw) {
                    int wi = w - 3 + kw;
                    float v = (wi >= 0 && wi < WW) ? row[wi] : 0.0f;
                    #pragma unroll
                    for (int j = 0; j < 4; ++j) {
                        const int kh = L - j;          // compile-time after unroll
                        if (kh >= 0 && kh <= 6)
                            attn[j] = fmaf(v, wsh[ic * 49 + kh * 7 + kw], attn[j]);
                    }
                }
            }
        }
        #pragma unroll
        for (int j = 0; j < 4; ++j)
            sig_lds[q * 4 + j][w] = 1.0f / (1.0f + __expf(-attn[j]));
    }
    __syncthreads();

    // ---------- Phase 3: channel-major waves -> 4 KB contiguous bursts ----
    // Wave wv owns channels {wv, wv+4, ...}; per channel it moves the block's
    // whole 8-row slab (4 KB contiguous) in 4 instructions. sig factors are
    // channel-invariant -> hoisted into 4 VGPR vectors.
    {
        const int wv = tid >> 6;           // 0..3
        const int ln = tid & 63;
        vfloat4 sgv[4];
        #pragma unroll
        for (int j = 0; j < 4; ++j) {
            int idx = ln + 64 * j;         // float4 index in 8x128 slab
            sgv[j] = *(const vfloat4*)&sig_lds[idx >> 5][(idx & 31) * 4];
        }
        const size_t slab_off = (size_t)h0 * WW;
        #pragma unroll 2
        for (int k = 31; k >= 0; --k) {    // descending c: MRU-first in L2
            const int c = wv + 4 * k;
            const vfloat4* ps = (const vfloat4*)(xb + (size_t)c * HWSZ + slab_off);
            vfloat4* po = (vfloat4*)(out + (size_t)b * CHW + (size_t)c * HWSZ + slab_off);
            vfloat4 v0 = ps[ln];
            vfloat4 v1 = ps[ln + 64];
            vfloat4 v2 = ps[ln + 128];
            vfloat4 v3 = ps[ln + 192];
            __builtin_nontemporal_store(v0 * sgv[0], po + ln);
            __builtin_nontemporal_store(v1 * sgv[1], po + ln + 64);
            __builtin_nontemporal_store(v2 * sgv[2], po + ln + 128);
            __builtin_nontemporal_store(v3 * sgv[3], po + ln + 192);
        }
    }
}

extern "C" void kernel_launch(void* const* d_in, const int* in_sizes, int n_in,
                              void* d_out, int out_size, void* d_ws, size_t ws_size,
                              hipStream_t stream) {
    const float* x  = (const float*)d_in[0];
    const float* cw = (const float*)d_in[1];
    float* out = (float*)d_out;

    sa_onepass<<<BB * (HH / RPB), 256, 0, stream>>>(x, cw, out);  // 512 blocks
}

// Round 12
// 133.101 us; speedup vs baseline: 1.3414x; 1.0583x over previous
//
#include <hip/hip_runtime.h>

#define BB 32
#define CC 128
#define HH 128
#define WW 128
#define HWSZ (HH * WW)          // 16384
#define CHW (CC * HWSZ)         // 2097152
#define S4 (HWSZ / 4)           // 4096
#define RPB 8                   // rows per block
#define HALO 14                 // RPB + 6

typedef float vfloat4 __attribute__((ext_vector_type(4)));

__device__ __forceinline__ vfloat4 fmax4(vfloat4 a, vfloat4 b) {
    vfloat4 r;
    r.x = fmaxf(a.x, b.x);
    r.y = fmaxf(a.y, b.y);
    r.z = fmaxf(a.z, b.z);
    r.w = fmaxf(a.w, b.w);
    return r;
}

// =================== PLAN A (ws >= 4 MiB): two kernels ===================

// K1: each row reduced exactly ONCE (no halo redundancy). 512 blocks.
// maps layout: [B][2][HH][WW] (ic 0 = avg, 1 = max).
__global__ __launch_bounds__(256) void k1_reduce(
    const float* __restrict__ x, float* __restrict__ maps) {
    const int tid = threadIdx.x;
    const int wg  = blockIdx.x;            // 0..511
    const int b   = wg >> 4;
    const int hb  = wg & 15;
    const int gh  = hb * RPB + (tid >> 5); // global row
    const int w4  = tid & 31;

    const vfloat4* p = (const vfloat4*)(x + (size_t)b * CHW + gh * WW) + w4;
    vfloat4 v = p[0];
    vfloat4 sum = v, mx = v;
    #pragma unroll 8
    for (int c = 1; c < CC; ++c) {
        vfloat4 t = p[(size_t)c * S4];
        sum += t;
        mx = fmax4(mx, t);
    }
    vfloat4 avg = sum * (1.0f / (float)CC);
    *((vfloat4*)(maps + ((size_t)b * 2 + 0) * HWSZ + gh * WW) + w4) = avg;
    *((vfloat4*)(maps + ((size_t)b * 2 + 1) * HWSZ + gh * WW) + w4) = mx;
}

// K2: stage 14 map-rows from global -> conv+sigmoid -> R11 channel-major multiply.
__global__ __launch_bounds__(256, 2) void k2_conv_mul(
    const float* __restrict__ x, const float* __restrict__ maps,
    const float* __restrict__ cw, float* __restrict__ out) {
    __shared__ float m_lds[2][HALO][WW];   // 14 KiB
    __shared__ float sig_lds[RPB][WW];     // 4 KiB
    __shared__ float wsh[2 * 49];

    const int tid = threadIdx.x;
    // XCD swizzle (same as champion): adjacent bands of a batch share an XCD.
    const int wg  = blockIdx.x;            // 0..511
    const int xcd = wg & 7;
    const int lin = wg >> 3;               // 0..63
    const int b   = xcd * 4 + (lin >> 4);  // 0..31
    const int hb  = lin & 15;              // 0..15
    const int h0  = hb * RPB;

    if (tid < 98) wsh[tid] = cw[tid];

    // ---- stage map halo rows h0-3 .. h0+10 (zero-fill OOB) ----
    for (int i = tid; i < 2 * HALO * 32; i += 256) {
        const int ic = i / (HALO * 32);
        const int rem = i - ic * (HALO * 32);
        const int rr = rem >> 5;           // 0..13
        const int w4 = rem & 31;
        const int gh = h0 - 3 + rr;
        vfloat4 v = {0.f, 0.f, 0.f, 0.f};
        if (gh >= 0 && gh < HH)
            v = *((const vfloat4*)(maps + ((size_t)b * 2 + ic) * HWSZ + gh * WW) + w4);
        *(vfloat4*)&m_lds[ic][rr][w4 * 4] = v;
    }
    __syncthreads();

    // ---- conv 7x7 + sigmoid, conflict-free (R8 layout) ----
    {
        const int q = tid >> 7;            // 0..1 -> rows q*4 .. q*4+3
        const int w = tid & 127;
        float attn[4] = {0.f, 0.f, 0.f, 0.f};
        #pragma unroll
        for (int ic = 0; ic < 2; ++ic) {
            #pragma unroll
            for (int L = 0; L < 10; ++L) {
                const float* row = &m_lds[ic][q * 4 + L][0];
                #pragma unroll
                for (int kw = 0; kw < 7; ++kw) {
                    int wi = w - 3 + kw;
                    float v = (wi >= 0 && wi < WW) ? row[wi] : 0.0f;
                    #pragma unroll
                    for (int j = 0; j < 4; ++j) {
                        const int kh = L - j;
                        if (kh >= 0 && kh <= 6)
                            attn[j] = fmaf(v, wsh[ic * 49 + kh * 7 + kw], attn[j]);
                    }
                }
            }
        }
        #pragma unroll
        for (int j = 0; j < 4; ++j)
            sig_lds[q * 4 + j][w] = 1.0f / (1.0f + __expf(-attn[j]));
    }
    __syncthreads();

    // ---- phase 3 (identical to R11): channel-major waves, 4 KB bursts ----
    {
        const float* xb = x + (size_t)b * CHW;
        const int wv = tid >> 6;           // 0..3
        const int ln = tid & 63;
        vfloat4 sgv[4];
        #pragma unroll
        for (int j = 0; j < 4; ++j) {
            int idx = ln + 64 * j;
            sgv[j] = *(const vfloat4*)&sig_lds[idx >> 5][(idx & 31) * 4];
        }
        const size_t slab_off = (size_t)h0 * WW;
        #pragma unroll 2
        for (int k = 31; k >= 0; --k) {
            const int c = wv + 4 * k;
            const vfloat4* ps = (const vfloat4*)(xb + (size_t)c * HWSZ + slab_off);
            vfloat4* po = (vfloat4*)(out + (size_t)b * CHW + (size_t)c * HWSZ + slab_off);
            vfloat4 v0 = ps[ln];
            vfloat4 v1 = ps[ln + 64];
            vfloat4 v2 = ps[ln + 128];
            vfloat4 v3 = ps[ln + 192];
            __builtin_nontemporal_store(v0 * sgv[0], po + ln);
            __builtin_nontemporal_store(v1 * sgv[1], po + ln + 64);
            __builtin_nontemporal_store(v2 * sgv[2], po + ln + 128);
            __builtin_nontemporal_store(v3 * sgv[3], po + ln + 192);
        }
    }
}

// =================== FALLBACK (ws < 4 MiB): R11 champion ===================
__global__ __launch_bounds__(256, 2) void sa_onepass(
    const float* __restrict__ x, const float* __restrict__ cw,
    float* __restrict__ out) {
    __shared__ float m_lds[2][HALO][WW];
    __shared__ float sig_lds[RPB][WW];
    __shared__ float wsh[2 * 49];

    const int tid = threadIdx.x;
    const int wg  = blockIdx.x;
    const int xcd = wg & 7;
    const int lin = wg >> 3;
    const int b   = xcd * 4 + (lin >> 4);
    const int hb  = lin & 15;
    const int h0  = hb * RPB;

    if (tid < 98) wsh[tid] = cw[tid];

    const int r0 = tid >> 5;
    const int w4 = tid & 31;
    const float* xb = x + (size_t)b * CHW;

    const bool actB = (r0 < HALO - 8);
    const int gh_a = h0 - 3 + r0;
    const int gh_b = h0 - 3 + r0 + 8;
    const bool okA = (gh_a >= 0) && (gh_a < HH);
    const bool okB = actB && (gh_b < HH);
    const int cha = gh_a < 0 ? 0 : (gh_a > HH - 1 ? HH - 1 : gh_a);
    const int chb = gh_b > HH - 1 ? HH - 1 : gh_b;

    const vfloat4* pA = (const vfloat4*)(xb + cha * WW) + w4;
    const vfloat4* pB = (const vfloat4*)(xb + chb * WW) + w4;

    vfloat4 sumA, mxA;
    {
        vfloat4 v = pA[0];
        sumA = v; mxA = v;
    }
    #pragma unroll 8
    for (int c = 1; c < CC; ++c) {
        vfloat4 v = pA[(size_t)c * S4];
        sumA += v;
        mxA = fmax4(mxA, v);
    }
    vfloat4 sumB = {0.f, 0.f, 0.f, 0.f}, mxB = sumB;
    if (actB) {
        vfloat4 v = pB[0];
        sumB = v; mxB = v;
        #pragma unroll 8
        for (int c = 1; c < CC; ++c) {
            vfloat4 t = pB[(size_t)c * S4];
            sumB += t;
            mxB = fmax4(mxB, t);
        }
    }

    const float invC = 1.0f / (float)CC;
    {
        vfloat4 avgA = sumA * invC;
        if (!okA) { avgA = (vfloat4){0,0,0,0}; mxA = (vfloat4){0,0,0,0}; }
        *(vfloat4*)&m_lds[0][r0][w4 * 4] = avgA;
        *(vfloat4*)&m_lds[1][r0][w4 * 4] = mxA;
        if (actB) {
            vfloat4 avgB = sumB * invC;
            if (!okB) { avgB = (vfloat4){0,0,0,0}; mxB = (vfloat4){0,0,0,0}; }
            *(vfloat4*)&m_lds[0][r0 + 8][w4 * 4] = avgB;
            *(vfloat4*)&m_lds[1][r0 + 8][w4 * 4] = mxB;
        }
    }
    __syncthreads();

    {
        const int q = tid >> 7;
        const int w = tid & 127;
        float attn[4] = {0.f, 0.f, 0.f, 0.f};
        #pragma unroll
        for (int ic = 0; ic < 2; ++ic) {
            #pragma unroll
            for (int L = 0; L < 10; ++L) {
                const float* row = &m_lds[ic][q * 4 + L][0];
                #pragma unroll
                for (int kw = 0; kw < 7; ++kw) {
                    int wi = w - 3 + kw;
                    float v = (wi >= 0 && wi < WW) ? row[wi] : 0.0f;
                    #pragma unroll
                    for (int j = 0; j < 4; ++j) {
                        const int kh = L - j;
                        if (kh >= 0 && kh <= 6)
                            attn[j] = fmaf(v, wsh[ic * 49 + kh * 7 + kw], attn[j]);
                    }
                }
            }
        }
        #pragma unroll
        for (int j = 0; j < 4; ++j)
            sig_lds[q * 4 + j][w] = 1.0f / (1.0f + __expf(-attn[j]));
    }
    __syncthreads();

    {
        const int wv = tid >> 6;
        const int ln = tid & 63;
        vfloat4 sgv[4];
        #pragma unroll
        for (int j = 0; j < 4; ++j) {
            int idx = ln + 64 * j;
            sgv[j] = *(const vfloat4*)&sig_lds[idx >> 5][(idx & 31) * 4];
        }
        const size_t slab_off = (size_t)h0 * WW;
        #pragma unroll 2
        for (int k = 31; k >= 0; --k) {
            const int c = wv + 4 * k;
            const vfloat4* ps = (const vfloat4*)(xb + (size_t)c * HWSZ + slab_off);
            vfloat4* po = (vfloat4*)(out + (size_t)b * CHW + (size_t)c * HWSZ + slab_off);
            vfloat4 v0 = ps[ln];
            vfloat4 v1 = ps[ln + 64];
            vfloat4 v2 = ps[ln + 128];
            vfloat4 v3 = ps[ln + 192];
            __builtin_nontemporal_store(v0 * sgv[0], po + ln);
            __builtin_nontemporal_store(v1 * sgv[1], po + ln + 64);
            __builtin_nontemporal_store(v2 * sgv[2], po + ln + 128);
            __builtin_nontemporal_store(v3 * sgv[3], po + ln + 192);
        }
    }
}

extern "C" void kernel_launch(void* const* d_in, const int* in_sizes, int n_in,
                              void* d_out, int out_size, void* d_ws, size_t ws_size,
                              hipStream_t stream) {
    const float* x  = (const float*)d_in[0];
    const float* cw = (const float*)d_in[1];
    float* out = (float*)d_out;

    const size_t maps_bytes = (size_t)BB * 2 * HWSZ * sizeof(float);  // 4 MiB
    if (ws_size >= maps_bytes) {
        float* maps = (float*)d_ws;
        k1_reduce<<<BB * (HH / RPB), 256, 0, stream>>>(x, maps);
        k2_conv_mul<<<BB * (HH / RPB), 256, 0, stream>>>(x, maps, cw, out);
    } else {
        sa_onepass<<<BB * (HH / RPB), 256, 0, stream>>>(x, cw, out);
    }
}